// Round 9
// baseline (442.590 us; speedup 1.0000x reference)
//
#include <hip/hip_runtime.h>

// Slater-determinant ordered sampler, D=512 sites, N=128 particles.
//
// Blocked (B=16) form of the verified N x N recursion:
//   per site: w = A p;  s = 1 - p.w;  <decision>;  A += w w^T / pivot.
// Exact left-looking identity (A symmetric throughout):
//   V = A0 P_B^T;  C = P_B V;  right-looking triangular scan on C fused
//   with the W-transform;  A += W diag(1/pivot) W^T.
//
// R9 (post R8: deltas track instruction count + exposed wait events):
//   - Vld2[64][34] interleaved V: element [l][2t+h] = V[l+64h][t], so each
//     Wp[t] pair is ONE aligned ds_read_b64 (16 b64, zero assembly movs;
//     4-way banks vs the old Vld[128][20] b128 8-way conflict -- candidate
//     source of the constant SQ_LDS_BANK_CONFLICT=10240)
//   - scan outputs buffered in LDS (pr_ld/kq_ld/pos_ld), flushed once at
//     the end: removes the per-block global-store vmcnt(0) drain that the
//     compiler emits before every s_barrier
//   - out-zeroing via float4 (128 -> 32 stores/thread)
//   - CldT row-pair written as one b64 per mm (32 -> 16 stores)
// FP values and op order bit-identical to R8/R5.
//
// Layout: wave v (of 8) owns A cols [16v,16v+16); lane l owns rows {l,l+64}.

#define DD 512
#define NN 128
#define NTHREADS 512
#define BB 16
#define NBLK (DD / BB)

typedef float v2f __attribute__((ext_vector_type(2)));

__device__ __forceinline__ float lane_bcast(float v, int l) {
  // l wave-uniform -> v_readlane_b32 (SGPR dest), bit-exact.
  return __int_as_float(__builtin_amdgcn_readlane(__float_as_int(v), l));
}
__device__ __forceinline__ void pk_fma_vv(v2f& acc, v2f a, v2f b) {
  asm("v_pk_fma_f32 %0, %1, %2, %0" : "+v"(acc) : "v"(a), "v"(b));
}
__device__ __forceinline__ void pk_fma_vs(v2f& acc, v2f a, v2f bs) {
  asm("v_pk_fma_f32 %0, %1, %2, %0" : "+v"(acc) : "v"(a), "s"(bs));
}
__device__ __forceinline__ v2f pk_mul_vv(v2f a, v2f b) {
  v2f d;
  asm("v_pk_mul_f32 %0, %1, %2" : "=v"(d) : "v"(a), "v"(b));
  return d;
}
__device__ __forceinline__ void pk_add_vv(v2f& acc, v2f a) {
  asm("v_pk_add_f32 %0, %1, %0" : "+v"(acc) : "v"(a));
}

// Packed pair reduce: component-wise identical to the scalar butterfly
// (same stage order 32,16,8,4,2,1; same xor partners).
__device__ __forceinline__ v2f wave_reduce_add64_pk(v2f sd) {
#if __has_builtin(__builtin_amdgcn_permlane32_swap)
  {
    unsigned xl = __float_as_uint(sd.x), xh = __float_as_uint(sd.y);
    auto rl = __builtin_amdgcn_permlane32_swap(xl, xl, false, false);
    auto rh = __builtin_amdgcn_permlane32_swap(xh, xh, false, false);
    v2f partner = {__uint_as_float(rl[1]), __uint_as_float(rh[1])};
    v2f self    = {__uint_as_float(rl[0]), __uint_as_float(rh[0])};
    sd = self;
    pk_add_vv(sd, partner);
  }
#else
  sd.x += __shfl_xor(sd.x, 32, 64);
  sd.y += __shfl_xor(sd.y, 32, 64);
#endif
#if __has_builtin(__builtin_amdgcn_permlane16_swap)
  {
    unsigned xl = __float_as_uint(sd.x), xh = __float_as_uint(sd.y);
    auto rl = __builtin_amdgcn_permlane16_swap(xl, xl, false, false);
    auto rh = __builtin_amdgcn_permlane16_swap(xh, xh, false, false);
    v2f partner = {__uint_as_float(rl[1]), __uint_as_float(rh[1])};
    v2f self    = {__uint_as_float(rl[0]), __uint_as_float(rh[0])};
    sd = self;
    pk_add_vv(sd, partner);
  }
#else
  sd.x += __shfl_xor(sd.x, 16, 64);
  sd.y += __shfl_xor(sd.y, 16, 64);
#endif
  sd.x += __int_as_float(__builtin_amdgcn_update_dpp(
      0, __float_as_int(sd.x), 0x128, 0xF, 0xF, true));
  sd.y += __int_as_float(__builtin_amdgcn_update_dpp(
      0, __float_as_int(sd.y), 0x128, 0xF, 0xF, true));
  {
    v2f partner = {
        __int_as_float(__builtin_amdgcn_ds_swizzle(__float_as_int(sd.x), 0x101F)),
        __int_as_float(__builtin_amdgcn_ds_swizzle(__float_as_int(sd.y), 0x101F))};
    pk_add_vv(sd, partner);
  }
  sd.x += __int_as_float(__builtin_amdgcn_update_dpp(
      0, __float_as_int(sd.x), 0x4E, 0xF, 0xF, true));
  sd.y += __int_as_float(__builtin_amdgcn_update_dpp(
      0, __float_as_int(sd.y), 0x4E, 0xF, 0xF, true));
  sd.x += __int_as_float(__builtin_amdgcn_update_dpp(
      0, __float_as_int(sd.x), 0xB1, 0xF, 0xF, true));
  sd.y += __int_as_float(__builtin_amdgcn_update_dpp(
      0, __float_as_int(sd.y), 0xB1, 0xF, 0xF, true));
  return sd;
}

__global__ __launch_bounds__(NTHREADS) void slater_scan_kernel(
    const float* __restrict__ P, const float* __restrict__ u,
    float* __restrict__ out) {
  const int tid   = threadIdx.x;
  const int wave  = tid >> 6;
  const int lane  = tid & 63;
  const int c0    = wave << 4;   // first A-column owned by this wave
  const bool lowhalf = (wave < 4);

  __shared__ __align__(16) float part[8][64][36];   // per-wave partial V
  __shared__ __align__(16) float Vld2[64][34];      // V interleaved: [l][2t+h]
  __shared__ __align__(16) float CldT[16][20];      // C transposed: [m][t]
  __shared__ __align__(16) float Pst[2][BB][NN];    // staged P blocks (dbuf)
  __shared__ __align__(16) float Wst[8][16][20];    // per-wave W-col stash
  __shared__ float pr_ld[DD];                       // buffered cond_prob values
  __shared__ int   kq_ld[DD];                       // buffered k-row per site
  __shared__ float pos_ld[NN];                      // buffered positions

  // Zero cond_probs region (harness poisons d_out) -- float4.
  {
    const float4 z4 = make_float4(0.f, 0.f, 0.f, 0.f);
    for (int j = tid; j < (NN * DD) / 4; j += NTHREADS) ((float4*)out)[j] = z4;
  }
  kq_ld[tid] = NN;   // "unwritten" marker (flush skips)

  // u in registers: lane holds entries {lane, lane+64}.
  const float ur0 = u[lane];
  const float ur1 = u[64 + lane];

  // Stage P block 0: thread -> one float4 (coalesced).
  const int sr = tid >> 5;          // staged row 0..15
  const int sc = (tid & 31) << 2;   // staged col (x4)
  *(float4*)&Pst[0][sr][sc] = *(const float4*)&P[sr * NN + sc];

  // A = I_N, column-pair packed.
  v2f A2r0[8], A2r1[8];
#pragma unroll
  for (int jp = 0; jp < 8; ++jp) {
    A2r0[jp] = (v2f){(lane == c0 + 2 * jp) ? 1.0f : 0.0f,
                     (lane == c0 + 2 * jp + 1) ? 1.0f : 0.0f};
    A2r1[jp] = (v2f){(lane + 64 == c0 + 2 * jp) ? 1.0f : 0.0f,
                     (lane + 64 == c0 + 2 * jp + 1) ? 1.0f : 0.0f};
  }

  // Decision state, replicated bit-identically in every thread.
  float ratio = 1.0f, cumul = 0.0f;
  int k = 0;

  __syncthreads();

  for (int blk = 0; blk < NBLK; ++blk) {
    const int i0  = blk * BB;
    const int buf = blk & 1;

    // Early-issue the next block's staging load (consumed pre-bar1).
    float4 stg;
    const bool do_stage = (blk + 1 < NBLK);
    if (do_stage) stg = *(const float4*)&P[(i0 + BB + sr) * NN + sc];

    // This wave's two C-row p values from the staged block.
    const int t2r = 2 * wave;
    const float pt0l = Pst[buf][t2r][lane];
    const float pt0h = Pst[buf][t2r][64 + lane];
    const float pt1l = Pst[buf][t2r + 1][lane];
    const float pt1h = Pst[buf][t2r + 1][64 + lane];

    // ---- phase 1: V-partials over this wave's 16 columns; P pairs via
    //      wave-uniform b128 LDS reads (HW broadcast). Straight-line.
    float pa0[16], pa1[16];
#pragma unroll
    for (int t = 0; t < 16; ++t) {
      const float4 q0 = *(const float4*)&Pst[buf][t][c0];
      const float4 q1 = *(const float4*)&Pst[buf][t][c0 + 4];
      const float4 q2 = *(const float4*)&Pst[buf][t][c0 + 8];
      const float4 q3 = *(const float4*)&Pst[buf][t][c0 + 12];
      const v2f pp0 = {q0.x, q0.y}, pp1 = {q0.z, q0.w};
      const v2f pp2 = {q1.x, q1.y}, pp3 = {q1.z, q1.w};
      const v2f pp4 = {q2.x, q2.y}, pp5 = {q2.z, q2.w};
      const v2f pp6 = {q3.x, q3.y}, pp7 = {q3.z, q3.w};
      v2f a0 = pk_mul_vv(A2r0[0], pp0);
      v2f a1 = pk_mul_vv(A2r1[0], pp0);
      pk_fma_vv(a0, A2r0[1], pp1); pk_fma_vv(a1, A2r1[1], pp1);
      pk_fma_vv(a0, A2r0[2], pp2); pk_fma_vv(a1, A2r1[2], pp2);
      pk_fma_vv(a0, A2r0[3], pp3); pk_fma_vv(a1, A2r1[3], pp3);
      pk_fma_vv(a0, A2r0[4], pp4); pk_fma_vv(a1, A2r1[4], pp4);
      pk_fma_vv(a0, A2r0[5], pp5); pk_fma_vv(a1, A2r1[5], pp5);
      pk_fma_vv(a0, A2r0[6], pp6); pk_fma_vv(a1, A2r1[6], pp6);
      pk_fma_vv(a0, A2r0[7], pp7); pk_fma_vv(a1, A2r1[7], pp7);
      pa0[t] = a0.x + a0.y;
      pa1[t] = a1.x + a1.y;
    }
    {
      float4* myp = (float4*)&part[wave][lane][0];
      myp[0] = make_float4(pa0[0],  pa0[1],  pa0[2],  pa0[3]);
      myp[1] = make_float4(pa0[4],  pa0[5],  pa0[6],  pa0[7]);
      myp[2] = make_float4(pa0[8],  pa0[9],  pa0[10], pa0[11]);
      myp[3] = make_float4(pa0[12], pa0[13], pa0[14], pa0[15]);
      myp[4] = make_float4(pa1[0],  pa1[1],  pa1[2],  pa1[3]);
      myp[5] = make_float4(pa1[4],  pa1[5],  pa1[6],  pa1[7]);
      myp[6] = make_float4(pa1[8],  pa1[9],  pa1[10], pa1[11]);
      myp[7] = make_float4(pa1[12], pa1[13], pa1[14], pa1[15]);
    }
    if (do_stage) *(float4*)&Pst[buf ^ 1][sr][sc] = stg;
    __syncthreads();  // barrier 1

    // ---- combine once into Vld2 (fixed v-order -> deterministic) ----
    // Vld2[l][2t+h] = V[l + 64h][t]: Wp pairs become single b64 reads.
    {
      const int r  = tid >> 2;            // output row 0..127
      const int qd = tid & 3;             // t-quad
      const int rl = r & 63;
      const int rh = (r >> 6) << 4;
      const int h  = r >> 6;
      v2f s01 = {0.0f, 0.0f}, s23 = {0.0f, 0.0f};
#pragma unroll
      for (int v = 0; v < 8; ++v) {
        const float4 x = *(const float4*)&part[v][rl][rh + 4 * qd];
        pk_add_vv(s01, (v2f){x.x, x.y});
        pk_add_vv(s23, (v2f){x.z, x.w});
      }
      const int cb = 8 * qd + h;          // 2*(4qd+e)+h for e=0..3
      Vld2[rl][cb + 0] = s01.x;
      Vld2[rl][cb + 2] = s01.y;
      Vld2[rl][cb + 4] = s23.x;
      Vld2[rl][cb + 6] = s23.y;
    }
    __syncthreads();  // barrier 2

    // ---- V rows into register pairs: 16 direct b64 reads, zero movs ----
    v2f Wp[16];
#pragma unroll
    for (int t = 0; t < 16; ++t)
      Wp[t] = *(const v2f*)&Vld2[lane][2 * t];

    // ---- C rows {2w, 2w+1}: C[t][m] = sum_r p_t[r] V[r][m] ----
    // Written TRANSPOSED: CldT[m][t2r..t2r+1] as one b64 per mm (lane0).
    {
      v2f cr[16];
#pragma unroll
      for (int mm = 0; mm < 16; ++mm) {
        const v2f wx = {Wp[mm].x, Wp[mm].x};
        const v2f wy = {Wp[mm].y, Wp[mm].y};
        v2f seed = pk_mul_vv((v2f){pt0h, pt1h}, wy);
        pk_fma_vv(seed, (v2f){pt0l, pt1l}, wx);
        cr[mm] = wave_reduce_add64_pk(seed);
      }
      if (lane == 0) {
#pragma unroll
        for (int mm = 0; mm < 16; ++mm)
          *(v2f*)&CldT[mm][t2r] = cr[mm];
      }
    }
    // uk for the scan's first iteration, hoisted above the barrier.
    int kidx = (k < NN) ? k : (NN - 1);
    float uk = (kidx < 64) ? lane_bcast(ur0, kidx & 63)
                           : lane_bcast(ur1, kidx & 63);
    __syncthreads();  // barrier 3

    // ---- fused decision scan + W-transform, RIGHT-LOOKING ----
    // Lane m owns column m of E; 4 b128 reads fetch the whole column.
    const int m = lane & 15;
    float Ereg[16];
    {
      const float4 e0 = *(const float4*)&CldT[m][0];
      const float4 e1 = *(const float4*)&CldT[m][4];
      const float4 e2 = *(const float4*)&CldT[m][8];
      const float4 e3 = *(const float4*)&CldT[m][12];
      Ereg[0]  = e0.x; Ereg[1]  = e0.y; Ereg[2]  = e0.z; Ereg[3]  = e0.w;
      Ereg[4]  = e1.x; Ereg[5]  = e1.y; Ereg[6]  = e1.z; Ereg[7]  = e1.w;
      Ereg[8]  = e2.x; Ereg[9]  = e2.y; Ereg[10] = e2.z; Ereg[11] = e2.w;
      Ereg[12] = e3.x; Ereg[13] = e3.y; Ereg[14] = e3.z; Ereg[15] = e3.w;
    }
    v2f SWp[16];
    bool done = false;
#pragma unroll
    for (int t = 0; t < 16; ++t) {
      const float s = 1.0f - lane_bcast(Ereg[t], t);   // E[t][t] from lane t
      const int i = i0 + t;
      const int last_allowed = DD - NN + k;
      const bool active = (k < NN) && (i <= last_allowed);
      const float pr = active ? (-(s - 1.0f) * ratio) : 0.0f;
      const bool occupy = active && ((cumul + pr >= uk) || (i == last_allowed));
      float pivot = occupy ? (s - 1.0f) : s;
      pivot = (fabsf(pivot) < 1e-30f) ? 1e-30f : pivot;
      const float invp = 1.0f / pivot;

      // Buffer outputs in LDS (no global stores -> no vmcnt drain at the
      // next barrier). Round-robined across waves.
      if (lane == 0 && wave == (t & 7)) {
        kq_ld[i] = k;          // pre-update k == reference k_rec row
        pr_ld[i] = pr;
        if (occupy) pos_ld[k] = (float)i;
      }

      ratio = occupy ? 1.0f : (active ? ratio * s : ratio);
      cumul = occupy ? 0.0f : (cumul + pr);
      k += occupy ? 1 : 0;
      if (k == NN) { done = true; break; }  // uniform; outputs complete

      // uk for iteration t+1, issued before the trailing-update block so
      // the readlane latency hides under it.
      {
        const int kidx2 = (k < NN) ? k : (NN - 1);
        uk = (kidx2 < 64) ? lane_bcast(ur0, kidx2 & 63)
                          : lane_bcast(ur1, kidx2 & 63);
      }

      // Pivot t's trailing updates (identical operands/order as R5).
      const float SDl = Ereg[t] * invp;
      SWp[t] = pk_mul_vv(Wp[t], (v2f){invp, invp});
#pragma unroll
      for (int t2 = t + 1; t2 < 16; ++t2) {
        const float djt2 = lane_bcast(Ereg[t], t2);   // D[t][t2]
        Ereg[t2] = fmaf(djt2, SDl, Ereg[t2]);
        pk_fma_vs(Wp[t2], SWp[t], (v2f){djt2, djt2});
      }
    }
    if (done) break;  // uniform across all threads -> flush epilogue

    // ---- stash this wave's 16 W-columns into its private LDS slab ----
    {
      const bool writer = ((lane >> 4) == (wave & 3));
      const int jl = lane & 15;
      if (writer) {
#pragma unroll
        for (int t = 0; t < 16; ++t)
          Wst[wave][t][jl] = lowhalf ? Wp[t].x : Wp[t].y;
      }
    }

    // ---- rank-16 update: A[r][c] += SW[r][t] * W[c][t] ----
    // W columns via wave-uniform b128 reads of the stash (straight-line).
#pragma unroll
    for (int t = 0; t < 16; ++t) {
      const float4 q0 = *(const float4*)&Wst[wave][t][0];
      const float4 q1 = *(const float4*)&Wst[wave][t][4];
      const float4 q2 = *(const float4*)&Wst[wave][t][8];
      const float4 q3 = *(const float4*)&Wst[wave][t][12];
      const v2f w0d = {SWp[t].x, SWp[t].x};
      const v2f w1d = {SWp[t].y, SWp[t].y};
      const v2f c01 = {q0.x, q0.y}, c23 = {q0.z, q0.w};
      const v2f c45 = {q1.x, q1.y}, c67 = {q1.z, q1.w};
      const v2f c89 = {q2.x, q2.y}, cab = {q2.z, q2.w};
      const v2f ccd = {q3.x, q3.y}, cef = {q3.z, q3.w};
      pk_fma_vv(A2r0[0], w0d, c01); pk_fma_vv(A2r1[0], w1d, c01);
      pk_fma_vv(A2r0[1], w0d, c23); pk_fma_vv(A2r1[1], w1d, c23);
      pk_fma_vv(A2r0[2], w0d, c45); pk_fma_vv(A2r1[2], w1d, c45);
      pk_fma_vv(A2r0[3], w0d, c67); pk_fma_vv(A2r1[3], w1d, c67);
      pk_fma_vv(A2r0[4], w0d, c89); pk_fma_vv(A2r1[4], w1d, c89);
      pk_fma_vv(A2r0[5], w0d, cab); pk_fma_vv(A2r1[5], w1d, cab);
      pk_fma_vv(A2r0[6], w0d, ccd); pk_fma_vv(A2r1[6], w1d, ccd);
      pk_fma_vv(A2r0[7], w0d, cef); pk_fma_vv(A2r1[7], w1d, cef);
    }
    // No trailing barrier: next block's LDS writes sit behind its own
    // barriers; this block's cross-wave LDS reads completed before bar3,
    // and Wst is strictly wave-private.
  }

  // ---- flush epilogue: one global-store pass for all buffered outputs ----
  __syncthreads();
  {
    const int kk = kq_ld[tid];
    if (kk < NN) out[kk * DD + tid] = pr_ld[tid];   // cond_probs[kk, site]
    if (tid < NN) out[NN * DD + tid] = pos_ld[tid]; // positions
  }
}

extern "C" void kernel_launch(void* const* d_in, const int* in_sizes, int n_in,
                              void* d_out, int out_size, void* d_ws,
                              size_t ws_size, hipStream_t stream) {
  const float* P = (const float*)d_in[0];  // (512, 128) row-major fp32
  const float* u = (const float*)d_in[1];  // (128,) fp32
  float* out = (float*)d_out;              // 65536 cond_probs + 128 positions
  hipLaunchKernelGGL(slater_scan_kernel, dim3(1), dim3(NTHREADS), 0, stream,
                     P, u, out);
}

// Round 11
// 421.598 us; speedup vs baseline: 1.0498x; 1.0498x over previous
//
#include <hip/hip_runtime.h>

// Slater-determinant ordered sampler, D=512 sites, N=128 particles.
//
// Blocked (B=16) form of the verified N x N recursion:
//   per site: w = A p;  s = 1 - p.w;  <decision>;  A += w w^T / pivot.
// Exact left-looking identity (A symmetric throughout):
//   V = A0 P_B^T;  C = P_B V;  right-looking triangular scan on C fused
//   with the W-transform;  A += W diag(1/pivot) W^T.
//
// R11 (post R10 correctness failure -- row_shr:4 shifts the wrong way:
// lane 0 got bound_ctrl 0, dropping half the dot product):
//   ^4 reduce stage now row_ror:4 (0x124), which is DIRECTION-PROOF:
//   after the exact ^32/^16/^8 stages the partials T_l depend only on
//   l&7 (period 8), and rotation by +-4 within the 16-row, taken mod 8,
//   equals (l&7)^4 in BOTH directions -- the exact xor partner, for all
//   64 lanes. (Same argument as the long-proven row_ror:8 for ^8.)
//   Reduce output is bit-identical to the R8 ds_swizzle butterfly; the
//   256 swizzle LDS-pipe ops/block move onto the VALU as DPP adds.
// Everything else identical to R10 = R8 + proven-safe micro-cuts
// (float4 out-zeroing, CldT row-pair b64 stores -- both passed in R9).
//
// Layout: wave v (of 8) owns A cols [16v,16v+16); lane l owns rows {l,l+64}.

#define DD 512
#define NN 128
#define NTHREADS 512
#define BB 16
#define NBLK (DD / BB)

typedef float v2f __attribute__((ext_vector_type(2)));

__device__ __forceinline__ float lane_bcast(float v, int l) {
  // l wave-uniform -> v_readlane_b32 (SGPR dest), bit-exact.
  return __int_as_float(__builtin_amdgcn_readlane(__float_as_int(v), l));
}
__device__ __forceinline__ void pk_fma_vv(v2f& acc, v2f a, v2f b) {
  asm("v_pk_fma_f32 %0, %1, %2, %0" : "+v"(acc) : "v"(a), "v"(b));
}
__device__ __forceinline__ void pk_fma_vs(v2f& acc, v2f a, v2f bs) {
  asm("v_pk_fma_f32 %0, %1, %2, %0" : "+v"(acc) : "v"(a), "s"(bs));
}
__device__ __forceinline__ v2f pk_mul_vv(v2f a, v2f b) {
  v2f d;
  asm("v_pk_mul_f32 %0, %1, %2" : "=v"(d) : "v"(a), "v"(b));
  return d;
}
__device__ __forceinline__ void pk_add_vv(v2f& acc, v2f a) {
  asm("v_pk_add_f32 %0, %1, %0" : "+v"(acc) : "v"(a));
}

// Packed pair reduce, ALL-LANE exact vs the xor butterfly:
//   ^32, ^16: permlane swaps (exact xor partners)
//   ^8:  row_ror:8  (+-8 mod 16 == ^8 -- exact, both rotation directions)
//   ^4:  row_ror:4  (after ^32/^16/^8 the partials have period 8;
//        +-4 mod 8 == ^4 -- exact, both rotation directions)
//   ^2, ^1: quad_perm (exact xor)
// Stage order and pairing identical to R8's butterfly -> bit-identical.
__device__ __forceinline__ v2f wave_reduce_add64_pk(v2f sd) {
#if __has_builtin(__builtin_amdgcn_permlane32_swap)
  {
    unsigned xl = __float_as_uint(sd.x), xh = __float_as_uint(sd.y);
    auto rl = __builtin_amdgcn_permlane32_swap(xl, xl, false, false);
    auto rh = __builtin_amdgcn_permlane32_swap(xh, xh, false, false);
    v2f partner = {__uint_as_float(rl[1]), __uint_as_float(rh[1])};
    v2f self    = {__uint_as_float(rl[0]), __uint_as_float(rh[0])};
    sd = self;
    pk_add_vv(sd, partner);
  }
#else
  sd.x += __shfl_xor(sd.x, 32, 64);
  sd.y += __shfl_xor(sd.y, 32, 64);
#endif
#if __has_builtin(__builtin_amdgcn_permlane16_swap)
  {
    unsigned xl = __float_as_uint(sd.x), xh = __float_as_uint(sd.y);
    auto rl = __builtin_amdgcn_permlane16_swap(xl, xl, false, false);
    auto rh = __builtin_amdgcn_permlane16_swap(xh, xh, false, false);
    v2f partner = {__uint_as_float(rl[1]), __uint_as_float(rh[1])};
    v2f self    = {__uint_as_float(rl[0]), __uint_as_float(rh[0])};
    sd = self;
    pk_add_vv(sd, partner);
  }
#else
  sd.x += __shfl_xor(sd.x, 16, 64);
  sd.y += __shfl_xor(sd.y, 16, 64);
#endif
  // ^8: row_ror:8 (0x128) -- exact xor-8 within each 16-lane row.
  sd.x += __int_as_float(__builtin_amdgcn_update_dpp(
      0, __float_as_int(sd.x), 0x128, 0xF, 0xF, true));
  sd.y += __int_as_float(__builtin_amdgcn_update_dpp(
      0, __float_as_int(sd.y), 0x128, 0xF, 0xF, true));
  // ^4: row_ror:4 (0x124) -- exact by the period-8 argument above.
  sd.x += __int_as_float(__builtin_amdgcn_update_dpp(
      0, __float_as_int(sd.x), 0x124, 0xF, 0xF, true));
  sd.y += __int_as_float(__builtin_amdgcn_update_dpp(
      0, __float_as_int(sd.y), 0x124, 0xF, 0xF, true));
  // ^2: quad_perm [2,3,0,1]; ^1: quad_perm [1,0,3,2] (exact xor).
  sd.x += __int_as_float(__builtin_amdgcn_update_dpp(
      0, __float_as_int(sd.x), 0x4E, 0xF, 0xF, true));
  sd.y += __int_as_float(__builtin_amdgcn_update_dpp(
      0, __float_as_int(sd.y), 0x4E, 0xF, 0xF, true));
  sd.x += __int_as_float(__builtin_amdgcn_update_dpp(
      0, __float_as_int(sd.x), 0xB1, 0xF, 0xF, true));
  sd.y += __int_as_float(__builtin_amdgcn_update_dpp(
      0, __float_as_int(sd.y), 0xB1, 0xF, 0xF, true));
  return sd;
}

__global__ __launch_bounds__(NTHREADS) void slater_scan_kernel(
    const float* __restrict__ P, const float* __restrict__ u,
    float* __restrict__ out) {
  const int tid   = threadIdx.x;
  const int wave  = tid >> 6;
  const int lane  = tid & 63;
  const int c0    = wave << 4;   // first A-column owned by this wave
  const bool lowhalf = (wave < 4);

  __shared__ __align__(16) float part[8][64][36];   // per-wave partial V
  __shared__ __align__(16) float Vld[128][20];      // combined V, row-major
  __shared__ __align__(16) float CldT[16][20];      // C transposed: [m][t]
  __shared__ __align__(16) float Pst[2][BB][NN];    // staged P blocks (dbuf)
  __shared__ __align__(16) float Wst[8][16][20];    // per-wave W-col stash

  // Zero cond_probs region (harness poisons d_out) -- float4.
  {
    const float4 z4 = make_float4(0.f, 0.f, 0.f, 0.f);
    for (int j = tid; j < (NN * DD) / 4; j += NTHREADS) ((float4*)out)[j] = z4;
  }

  // u in registers: lane holds entries {lane, lane+64}.
  const float ur0 = u[lane];
  const float ur1 = u[64 + lane];

  // Stage P block 0: thread -> one float4 (coalesced).
  const int sr = tid >> 5;          // staged row 0..15
  const int sc = (tid & 31) << 2;   // staged col (x4)
  *(float4*)&Pst[0][sr][sc] = *(const float4*)&P[sr * NN + sc];

  // A = I_N, column-pair packed.
  v2f A2r0[8], A2r1[8];
#pragma unroll
  for (int jp = 0; jp < 8; ++jp) {
    A2r0[jp] = (v2f){(lane == c0 + 2 * jp) ? 1.0f : 0.0f,
                     (lane == c0 + 2 * jp + 1) ? 1.0f : 0.0f};
    A2r1[jp] = (v2f){(lane + 64 == c0 + 2 * jp) ? 1.0f : 0.0f,
                     (lane + 64 == c0 + 2 * jp + 1) ? 1.0f : 0.0f};
  }

  // Decision state, replicated bit-identically in every thread.
  float ratio = 1.0f, cumul = 0.0f;
  int k = 0;

  __syncthreads();

  for (int blk = 0; blk < NBLK; ++blk) {
    const int i0  = blk * BB;
    const int buf = blk & 1;

    // Early-issue the next block's staging load (consumed pre-bar1).
    float4 stg;
    const bool do_stage = (blk + 1 < NBLK);
    if (do_stage) stg = *(const float4*)&P[(i0 + BB + sr) * NN + sc];

    // This wave's two C-row p values from the staged block.
    const int t2r = 2 * wave;
    const float pt0l = Pst[buf][t2r][lane];
    const float pt0h = Pst[buf][t2r][64 + lane];
    const float pt1l = Pst[buf][t2r + 1][lane];
    const float pt1h = Pst[buf][t2r + 1][64 + lane];

    // ---- phase 1: V-partials over this wave's 16 columns; P pairs via
    //      wave-uniform b128 LDS reads (HW broadcast). Straight-line.
    float pa0[16], pa1[16];
#pragma unroll
    for (int t = 0; t < 16; ++t) {
      const float4 q0 = *(const float4*)&Pst[buf][t][c0];
      const float4 q1 = *(const float4*)&Pst[buf][t][c0 + 4];
      const float4 q2 = *(const float4*)&Pst[buf][t][c0 + 8];
      const float4 q3 = *(const float4*)&Pst[buf][t][c0 + 12];
      const v2f pp0 = {q0.x, q0.y}, pp1 = {q0.z, q0.w};
      const v2f pp2 = {q1.x, q1.y}, pp3 = {q1.z, q1.w};
      const v2f pp4 = {q2.x, q2.y}, pp5 = {q2.z, q2.w};
      const v2f pp6 = {q3.x, q3.y}, pp7 = {q3.z, q3.w};
      v2f a0 = pk_mul_vv(A2r0[0], pp0);
      v2f a1 = pk_mul_vv(A2r1[0], pp0);
      pk_fma_vv(a0, A2r0[1], pp1); pk_fma_vv(a1, A2r1[1], pp1);
      pk_fma_vv(a0, A2r0[2], pp2); pk_fma_vv(a1, A2r1[2], pp2);
      pk_fma_vv(a0, A2r0[3], pp3); pk_fma_vv(a1, A2r1[3], pp3);
      pk_fma_vv(a0, A2r0[4], pp4); pk_fma_vv(a1, A2r1[4], pp4);
      pk_fma_vv(a0, A2r0[5], pp5); pk_fma_vv(a1, A2r1[5], pp5);
      pk_fma_vv(a0, A2r0[6], pp6); pk_fma_vv(a1, A2r1[6], pp6);
      pk_fma_vv(a0, A2r0[7], pp7); pk_fma_vv(a1, A2r1[7], pp7);
      pa0[t] = a0.x + a0.y;
      pa1[t] = a1.x + a1.y;
    }
    {
      float4* myp = (float4*)&part[wave][lane][0];
      myp[0] = make_float4(pa0[0],  pa0[1],  pa0[2],  pa0[3]);
      myp[1] = make_float4(pa0[4],  pa0[5],  pa0[6],  pa0[7]);
      myp[2] = make_float4(pa0[8],  pa0[9],  pa0[10], pa0[11]);
      myp[3] = make_float4(pa0[12], pa0[13], pa0[14], pa0[15]);
      myp[4] = make_float4(pa1[0],  pa1[1],  pa1[2],  pa1[3]);
      myp[5] = make_float4(pa1[4],  pa1[5],  pa1[6],  pa1[7]);
      myp[6] = make_float4(pa1[8],  pa1[9],  pa1[10], pa1[11]);
      myp[7] = make_float4(pa1[12], pa1[13], pa1[14], pa1[15]);
    }
    if (do_stage) *(float4*)&Pst[buf ^ 1][sr][sc] = stg;
    __syncthreads();  // barrier 1

    // ---- combine once into Vld[r][t] (fixed v-order -> deterministic) ----
    {
      const int r  = tid >> 2;            // output row 0..127
      const int qd = tid & 3;             // t-quad
      const int rl = r & 63;
      const int rh = (r >> 6) << 4;
      v2f s01 = {0.0f, 0.0f}, s23 = {0.0f, 0.0f};
#pragma unroll
      for (int v = 0; v < 8; ++v) {
        const float4 x = *(const float4*)&part[v][rl][rh + 4 * qd];
        pk_add_vv(s01, (v2f){x.x, x.y});
        pk_add_vv(s23, (v2f){x.z, x.w});
      }
      *(float4*)&Vld[r][4 * qd] = make_float4(s01.x, s01.y, s23.x, s23.y);
    }
    __syncthreads();  // barrier 2

    // ---- V rows into register pairs via 8 b128 reads ----
    v2f Wp[16];
    {
      const float4 x0 = *(const float4*)&Vld[lane][0];
      const float4 x1 = *(const float4*)&Vld[lane][4];
      const float4 x2 = *(const float4*)&Vld[lane][8];
      const float4 x3 = *(const float4*)&Vld[lane][12];
      const float4 y0 = *(const float4*)&Vld[lane + 64][0];
      const float4 y1 = *(const float4*)&Vld[lane + 64][4];
      const float4 y2 = *(const float4*)&Vld[lane + 64][8];
      const float4 y3 = *(const float4*)&Vld[lane + 64][12];
      Wp[0]  = (v2f){x0.x, y0.x}; Wp[1]  = (v2f){x0.y, y0.y};
      Wp[2]  = (v2f){x0.z, y0.z}; Wp[3]  = (v2f){x0.w, y0.w};
      Wp[4]  = (v2f){x1.x, y1.x}; Wp[5]  = (v2f){x1.y, y1.y};
      Wp[6]  = (v2f){x1.z, y1.z}; Wp[7]  = (v2f){x1.w, y1.w};
      Wp[8]  = (v2f){x2.x, y2.x}; Wp[9]  = (v2f){x2.y, y2.y};
      Wp[10] = (v2f){x2.z, y2.z}; Wp[11] = (v2f){x2.w, y2.w};
      Wp[12] = (v2f){x3.x, y3.x}; Wp[13] = (v2f){x3.y, y3.y};
      Wp[14] = (v2f){x3.z, y3.z}; Wp[15] = (v2f){x3.w, y3.w};
    }

    // ---- C rows {2w, 2w+1}: C[t][m] = sum_r p_t[r] V[r][m] ----
    // Written TRANSPOSED: CldT[m][t2r..t2r+1] as one b64 per mm (lane0).
    {
      v2f cr[16];
#pragma unroll
      for (int mm = 0; mm < 16; ++mm) {
        const v2f wx = {Wp[mm].x, Wp[mm].x};
        const v2f wy = {Wp[mm].y, Wp[mm].y};
        v2f seed = pk_mul_vv((v2f){pt0h, pt1h}, wy);
        pk_fma_vv(seed, (v2f){pt0l, pt1l}, wx);
        cr[mm] = wave_reduce_add64_pk(seed);
      }
      if (lane == 0) {
#pragma unroll
        for (int mm = 0; mm < 16; ++mm)
          *(v2f*)&CldT[mm][t2r] = cr[mm];   // 80B rows: 8B-aligned stores
      }
    }
    // uk for the scan's first iteration, hoisted above the barrier.
    int kidx = (k < NN) ? k : (NN - 1);
    float uk = (kidx < 64) ? lane_bcast(ur0, kidx & 63)
                           : lane_bcast(ur1, kidx & 63);
    __syncthreads();  // barrier 3

    // ---- fused decision scan + W-transform, RIGHT-LOOKING ----
    // Lane m owns column m of E; 4 b128 reads fetch the whole column.
    const int m = lane & 15;
    float Ereg[16];
    {
      const float4 e0 = *(const float4*)&CldT[m][0];
      const float4 e1 = *(const float4*)&CldT[m][4];
      const float4 e2 = *(const float4*)&CldT[m][8];
      const float4 e3 = *(const float4*)&CldT[m][12];
      Ereg[0]  = e0.x; Ereg[1]  = e0.y; Ereg[2]  = e0.z; Ereg[3]  = e0.w;
      Ereg[4]  = e1.x; Ereg[5]  = e1.y; Ereg[6]  = e1.z; Ereg[7]  = e1.w;
      Ereg[8]  = e2.x; Ereg[9]  = e2.y; Ereg[10] = e2.z; Ereg[11] = e2.w;
      Ereg[12] = e3.x; Ereg[13] = e3.y; Ereg[14] = e3.z; Ereg[15] = e3.w;
    }
    v2f SWp[16];
    bool done = false;
#pragma unroll
    for (int t = 0; t < 16; ++t) {
      const float s = 1.0f - lane_bcast(Ereg[t], t);   // E[t][t] from lane t
      const int i = i0 + t;
      const int last_allowed = DD - NN + k;
      const bool active = (k < NN) && (i <= last_allowed);
      const float pr = active ? (-(s - 1.0f) * ratio) : 0.0f;
      const bool occupy = active && ((cumul + pr >= uk) || (i == last_allowed));
      float pivot = occupy ? (s - 1.0f) : s;
      pivot = (fabsf(pivot) < 1e-30f) ? 1e-30f : pivot;
      const float invp = 1.0f / pivot;

      // Out-stores round-robined across waves (balances bar1 arrival).
      if (lane == 0 && wave == (t & 7)) {
        if (k < NN) out[k * DD + i] = pr;         // cond_probs[k, i]
        if (occupy) out[NN * DD + k] = (float)i;  // positions[k]
      }

      ratio = occupy ? 1.0f : (active ? ratio * s : ratio);
      cumul = occupy ? 0.0f : (cumul + pr);
      k += occupy ? 1 : 0;
      if (k == NN) { done = true; break; }  // uniform; outputs complete

      // uk for iteration t+1, issued before the trailing-update block so
      // the readlane latency hides under it.
      {
        const int kidx2 = (k < NN) ? k : (NN - 1);
        uk = (kidx2 < 64) ? lane_bcast(ur0, kidx2 & 63)
                          : lane_bcast(ur1, kidx2 & 63);
      }

      // Pivot t's trailing updates (identical operands/order as R5).
      const float SDl = Ereg[t] * invp;
      SWp[t] = pk_mul_vv(Wp[t], (v2f){invp, invp});
#pragma unroll
      for (int t2 = t + 1; t2 < 16; ++t2) {
        const float djt2 = lane_bcast(Ereg[t], t2);   // D[t][t2]
        Ereg[t2] = fmaf(djt2, SDl, Ereg[t2]);
        pk_fma_vs(Wp[t2], SWp[t], (v2f){djt2, djt2});
      }
    }
    if (done) return;  // uniform across all threads

    // ---- stash this wave's 16 W-columns into its private LDS slab ----
    {
      const bool writer = ((lane >> 4) == (wave & 3));
      const int jl = lane & 15;
      if (writer) {
#pragma unroll
        for (int t = 0; t < 16; ++t)
          Wst[wave][t][jl] = lowhalf ? Wp[t].x : Wp[t].y;
      }
    }

    // ---- rank-16 update: A[r][c] += SW[r][t] * W[c][t] ----
    // W columns via wave-uniform b128 reads of the stash (straight-line).
#pragma unroll
    for (int t = 0; t < 16; ++t) {
      const float4 q0 = *(const float4*)&Wst[wave][t][0];
      const float4 q1 = *(const float4*)&Wst[wave][t][4];
      const float4 q2 = *(const float4*)&Wst[wave][t][8];
      const float4 q3 = *(const float4*)&Wst[wave][t][12];
      const v2f w0d = {SWp[t].x, SWp[t].x};
      const v2f w1d = {SWp[t].y, SWp[t].y};
      const v2f c01 = {q0.x, q0.y}, c23 = {q0.z, q0.w};
      const v2f c45 = {q1.x, q1.y}, c67 = {q1.z, q1.w};
      const v2f c89 = {q2.x, q2.y}, cab = {q2.z, q2.w};
      const v2f ccd = {q3.x, q3.y}, cef = {q3.z, q3.w};
      pk_fma_vv(A2r0[0], w0d, c01); pk_fma_vv(A2r1[0], w1d, c01);
      pk_fma_vv(A2r0[1], w0d, c23); pk_fma_vv(A2r1[1], w1d, c23);
      pk_fma_vv(A2r0[2], w0d, c45); pk_fma_vv(A2r1[2], w1d, c45);
      pk_fma_vv(A2r0[3], w0d, c67); pk_fma_vv(A2r1[3], w1d, c67);
      pk_fma_vv(A2r0[4], w0d, c89); pk_fma_vv(A2r1[4], w1d, c89);
      pk_fma_vv(A2r0[5], w0d, cab); pk_fma_vv(A2r1[5], w1d, cab);
      pk_fma_vv(A2r0[6], w0d, ccd); pk_fma_vv(A2r1[6], w1d, ccd);
      pk_fma_vv(A2r0[7], w0d, cef); pk_fma_vv(A2r1[7], w1d, cef);
    }
    // No trailing barrier: next block's LDS writes sit behind its own
    // barriers; this block's cross-wave LDS reads completed before bar3,
    // and Wst is strictly wave-private.
  }
}

extern "C" void kernel_launch(void* const* d_in, const int* in_sizes, int n_in,
                              void* d_out, int out_size, void* d_ws,
                              size_t ws_size, hipStream_t stream) {
  const float* P = (const float*)d_in[0];  // (512, 128) row-major fp32
  const float* u = (const float*)d_in[1];  // (128,) fp32
  float* out = (float*)d_out;              // 65536 cond_probs + 128 positions
  hipLaunchKernelGGL(slater_scan_kernel, dim3(1), dim3(NTHREADS), 0, stream,
                     P, u, out);
}